// Round 15
// baseline (698.249 us; speedup 1.0000x reference)
//
#include <hip/hip_runtime.h>
#include <cmath>

#define DIMS 2048
#define SEQ  8192
#define NB   2
#define HEADS 16
#define HD   128
#define WINW 256
#define MROWS 16384  // NB*SEQ
#define NCH  32      // SEQ/WINW

using bf16x8 = __attribute__((ext_vector_type(8))) short;
using f32x4  = __attribute__((ext_vector_type(4))) float;

__device__ __forceinline__ unsigned short f2bf(float f) {
  unsigned int u = __float_as_uint(f);
  u += 0x7FFF + ((u >> 16) & 1);
  return (unsigned short)(u >> 16);
}

__device__ __forceinline__ void async16(const unsigned short* g, unsigned short* l) {
  __builtin_amdgcn_global_load_lds((const __attribute__((address_space(1))) void*)g,
                                   (__attribute__((address_space(3))) void*)l,
                                   16, 0, 0);
}

#define BAR() __builtin_amdgcn_s_barrier()
#define WAIT_LGKM0() do { asm volatile("s_waitcnt lgkmcnt(0)" ::: "memory"); \
                          __builtin_amdgcn_sched_barrier(0); } while (0)
#define WAIT_LGKM(n) do { asm volatile("s_waitcnt lgkmcnt(" #n ")" ::: "memory"); \
                          __builtin_amdgcn_sched_barrier(0); } while (0)
#define ORDER() asm volatile("" ::: "memory")
#define WAIT_VM(n) asm volatile("s_waitcnt vmcnt(" #n ")" ::: "memory")
#define MFMA16(a, b, c) __builtin_amdgcn_mfma_f32_16x16x32_bf16(a, b, c, 0, 0, 0)

// ---------------- fused prep: weight transpose+convert / hidden f32->bf16 / RoPE table
__global__ __launch_bounds__(256) void prep(
    const float* __restrict__ w0, const float* __restrict__ w1,
    const float* __restrict__ w2, const float* __restrict__ w3,
    const float* __restrict__ H,
    unsigned short* __restrict__ Wt, unsigned short* __restrict__ Hb,
    float* __restrict__ cosT, float* __restrict__ sinT) {
  __shared__ unsigned short tile[64][65];
  const int bid = blockIdx.x;
  const int t = threadIdx.x;
  if (bid < 4096) {
    const int z = bid & 3;
    const int rest = bid >> 2;
    const int n0 = (rest & 31) * 64, k0 = (rest >> 5) * 64;
    const float* W = (z == 0) ? w0 : (z == 1) ? w1 : (z == 2) ? w2 : w3;
    unsigned short* O = Wt + (size_t)z * DIMS * DIMS;
    #pragma unroll
    for (int p = 0; p < 16; ++p) {
      int i = p * 4 + (t >> 6);
      int j = t & 63;
      tile[i][j] = f2bf(W[(size_t)(k0 + i) * DIMS + n0 + j]);
    }
    __syncthreads();
    #pragma unroll
    for (int p = 0; p < 16; ++p) {
      int a = p * 4 + (t >> 6);
      int b = t & 63;
      O[(size_t)(n0 + a) * DIMS + k0 + b] = tile[b][a];
    }
  } else if (bid < 6144) {
    const long n4 = (long)MROWS * DIMS / 4;
    long i = (long)(bid - 4096) * 256 + t;
    for (; i < n4; i += 524288) {
      float4 v = ((const float4*)H)[i];
      ushort4 o;
      o.x = f2bf(v.x); o.y = f2bf(v.y); o.z = f2bf(v.z); o.w = f2bf(v.w);
      ((ushort4*)Hb)[i] = o;
    }
  } else {
    int tl = (bid - 6144) * 256 + t;  // 524288 total
    int pos = tl >> 6, i = tl & 63;
    float inv = powf(10000.0f, -(float)i / 64.0f);
    float ang = (float)pos * inv;
    float s, cc;
    __sincosf(ang, &s, &cc);
    cosT[tl] = cc;
    sinT[tl] = s;
  }
}

// ---------------- 256x256 8-phase GEMM (R11 exact: R5 schedule + split-lgkm) --------
// Measured best: QKV 384us, 0 conflicts, MfmaUtil 49%. Register budget HARD 256/wave:
// no cross-phase fragment liveness (R7/R9 spilled); no phase merging (R12 -2%); no
// 32x32 MFMA (R6 conflicts). DO NOT restructure.
template<int MODE>
__global__ __launch_bounds__(512, 2) void gemm256(
    const unsigned short* __restrict__ A,
    const unsigned short* __restrict__ WtAll,
    unsigned short* __restrict__ OutB,
    float* __restrict__ OutF,
    const float* __restrict__ cosT,
    const float* __restrict__ sinT) {
  __shared__ __align__(1024) unsigned short lds[65536];  // 128 KiB
  unsigned short* const As0 = lds;           // buf0 A [256][64]
  unsigned short* const Bs0 = lds + 16384;   // buf0 B
  unsigned short* const As1 = lds + 32768;   // buf1 A
  unsigned short* const Bs1 = lds + 49152;   // buf1 B

  const int tid = threadIdx.x;
  const int wid = tid >> 6, lane = tid & 63;
  const int lo = lane & 15, hi = lane >> 4;
  const int wm = wid >> 2, wn = wid & 3;
  const int flip = (lo & 7) << 4;  // read-side XOR: byte ^= (row&7)<<4

  // T1: bijective XCD swizzle (grid % 8 == 0 for both modes)
  const int nwg = gridDim.x;
  const int orig = blockIdx.x;
  const int bid = (orig & 7) * (nwg >> 3) + (orig >> 3);

  // z-major mapping: per XCD ~24 A-panels + one z's B matrix in L2
  int by, bx, z;
  if (MODE == 0) {
    z = bid >> 9;
    by = (bid & 511) >> 3;
    bx = bid & 7;
  } else {
    by = bid >> 3; bx = bid & 7; z = 3;
  }
  const int m0 = by * 256, n0 = bx * 256;
  const unsigned short* const Ag = A;
  const unsigned short* const Bg = WtAll + (size_t)z * DIMS * DIMS;

  f32x4 acc[8][4];
  #pragma unroll
  for (int i = 0; i < 8; ++i)
    #pragma unroll
    for (int j = 0; j < 4; ++j)
      acc[i][j] = (f32x4){0.f, 0.f, 0.f, 0.f};

  auto stage_half = [&](const unsigned short* __restrict__ G, int grow0, int tile,
                        unsigned short* dst) {
    const int k0 = tile * 64;
    #pragma unroll
    for (int h8 = 0; h8 < 2; ++h8) {
      const int c = h8 * 8 + wid;
      const int row = c * 8 + (lane >> 3);
      const int col8 = (lane & 7) ^ (lane >> 3);
      async16(G + (size_t)(grow0 + row) * DIMS + k0 + col8 * 8, dst + c * 512);
    }
  };
  auto rdA = [&](const unsigned short* base, int i, int kk) -> bf16x8 {
    const int r = i * 32 + wm * 16 + lo;
    const int cb = (kk * 64 + hi * 16) ^ flip;
    return *(const bf16x8*)((const char*)base + r * 128 + cb);
  };
  auto rdB = [&](const unsigned short* base, int j, int kk) -> bf16x8 {
    const int r = j * 64 + wn * 16 + lo;
    const int cb = (kk * 64 + hi * 16) ^ flip;
    return *(const bf16x8*)((const char*)base + r * 128 + cb);
  };

  bf16x8 aq[4][2], b0[2][2], b1[2][2];

  // prologue: tile0 full + {A0,B0,B1}(1); vmcnt(6) => tile0 landed, 3 halves in flight
  stage_half(Ag, m0,       0, As0);
  stage_half(Bg, n0,       0, Bs0);
  stage_half(Ag, m0 + 128, 0, As0 + 8192);
  stage_half(Bg, n0 + 128, 0, Bs0 + 8192);
  stage_half(Ag, m0,       1, As1);
  stage_half(Bg, n0,       1, Bs1);
  stage_half(Bg, n0 + 128, 1, Bs1 + 8192);
  WAIT_VM(6);
  BAR();

  #pragma unroll 1
  for (int it = 0; it < 16; ++it) {
    const int t = 2 * it;
    const bool pre = (it < 15);
    // ---- P1: aq+b0 (kk0 then kk1); stage A1(t+1); kk0 MFMA under kk1-read latency
    #pragma unroll
    for (int i = 0; i < 4; ++i) aq[i][0] = rdA(As0, i, 0);
    #pragma unroll
    for (int j = 0; j < 2; ++j) b0[j][0] = rdB(Bs0, j, 0);
    ORDER();
    #pragma unroll
    for (int i = 0; i < 4; ++i) aq[i][1] = rdA(As0, i, 1);
    #pragma unroll
    for (int j = 0; j < 2; ++j) b0[j][1] = rdB(Bs0, j, 1);
    stage_half(Ag, m0 + 128, t + 1, As1 + 8192);
    WAIT_LGKM(6);
    __builtin_amdgcn_s_setprio(1);
    #pragma unroll
    for (int i = 0; i < 4; ++i)
      #pragma unroll
      for (int j = 0; j < 2; ++j)
        acc[i][j] = MFMA16(aq[i][0], b0[j][0], acc[i][j]);
    WAIT_LGKM0();
    #pragma unroll
    for (int i = 0; i < 4; ++i)
      #pragma unroll
      for (int j = 0; j < 2; ++j)
        acc[i][j] = MFMA16(aq[i][1], b0[j][1], acc[i][j]);
    __builtin_amdgcn_s_setprio(0);
    BAR();
    // ---- P2: b1 (kk0, kk1); stage A0(t+2)
    #pragma unroll
    for (int j = 0; j < 2; ++j) b1[j][0] = rdB(Bs0, 2 + j, 0);
    ORDER();
    #pragma unroll
    for (int j = 0; j < 2; ++j) b1[j][1] = rdB(Bs0, 2 + j, 1);
    if (pre) stage_half(Ag, m0, t + 2, As0);
    WAIT_LGKM(2);
    __builtin_amdgcn_s_setprio(1);
    #pragma unroll
    for (int i = 0; i < 4; ++i)
      #pragma unroll
      for (int j = 0; j < 2; ++j)
        acc[i][2 + j] = MFMA16(aq[i][0], b1[j][0], acc[i][2 + j]);
    WAIT_LGKM0();
    #pragma unroll
    for (int i = 0; i < 4; ++i)
      #pragma unroll
      for (int j = 0; j < 2; ++j)
        acc[i][2 + j] = MFMA16(aq[i][1], b1[j][1], acc[i][2 + j]);
    __builtin_amdgcn_s_setprio(0);
    BAR();
    // ---- P3: aq half1 (kk0, kk1); stage B0(t+2)
    #pragma unroll
    for (int i = 0; i < 4; ++i) aq[i][0] = rdA(As0, 4 + i, 0);
    ORDER();
    #pragma unroll
    for (int i = 0; i < 4; ++i) aq[i][1] = rdA(As0, 4 + i, 1);
    if (pre) stage_half(Bg, n0, t + 2, Bs0);
    WAIT_LGKM(4);
    __builtin_amdgcn_s_setprio(1);
    #pragma unroll
    for (int i = 0; i < 4; ++i)
      #pragma unroll
      for (int j = 0; j < 2; ++j)
        acc[4 + i][j] = MFMA16(aq[i][0], b0[j][0], acc[4 + i][j]);
    WAIT_LGKM0();
    #pragma unroll
    for (int i = 0; i < 4; ++i)
      #pragma unroll
      for (int j = 0; j < 2; ++j)
        acc[4 + i][j] = MFMA16(aq[i][1], b0[j][1], acc[4 + i][j]);
    __builtin_amdgcn_s_setprio(0);
    BAR();
    // ---- P4: stage B1(t+2); MFMA; counted vmcnt
    if (pre) stage_half(Bg, n0 + 128, t + 2, Bs0 + 8192);
    __builtin_amdgcn_s_setprio(1);
    #pragma unroll
    for (int kk = 0; kk < 2; ++kk)
      #pragma unroll
      for (int i = 0; i < 4; ++i)
        #pragma unroll
        for (int j = 0; j < 2; ++j)
          acc[4 + i][2 + j] = MFMA16(aq[i][kk], b1[j][kk], acc[4 + i][2 + j]);
    __builtin_amdgcn_s_setprio(0);
    if (it == 15) { WAIT_VM(0); } else { WAIT_VM(6); }
    BAR();
    // ---- P5 (buf1 mirror of P1)
    #pragma unroll
    for (int i = 0; i < 4; ++i) aq[i][0] = rdA(As1, i, 0);
    #pragma unroll
    for (int j = 0; j < 2; ++j) b0[j][0] = rdB(Bs1, j, 0);
    ORDER();
    #pragma unroll
    for (int i = 0; i < 4; ++i) aq[i][1] = rdA(As1, i, 1);
    #pragma unroll
    for (int j = 0; j < 2; ++j) b0[j][1] = rdB(Bs1, j, 1);
    if (pre) stage_half(Ag, m0 + 128, t + 2, As0 + 8192);
    WAIT_LGKM(6);
    __builtin_amdgcn_s_setprio(1);
    #pragma unroll
    for (int i = 0; i < 4; ++i)
      #pragma unroll
      for (int j = 0; j < 2; ++j)
        acc[i][j] = MFMA16(aq[i][0], b0[j][0], acc[i][j]);
    WAIT_LGKM0();
    #pragma unroll
    for (int i = 0; i < 4; ++i)
      #pragma unroll
      for (int j = 0; j < 2; ++j)
        acc[i][j] = MFMA16(aq[i][1], b0[j][1], acc[i][j]);
    __builtin_amdgcn_s_setprio(0);
    BAR();
    // ---- P6 (mirror of P2)
    #pragma unroll
    for (int j = 0; j < 2; ++j) b1[j][0] = rdB(Bs1, 2 + j, 0);
    ORDER();
    #pragma unroll
    for (int j = 0; j < 2; ++j) b1[j][1] = rdB(Bs1, 2 + j, 1);
    if (pre) stage_half(Ag, m0, t + 3, As1);
    WAIT_LGKM(2);
    __builtin_amdgcn_s_setprio(1);
    #pragma unroll
    for (int i = 0; i < 4; ++i)
      #pragma unroll
      for (int j = 0; j < 2; ++j)
        acc[i][2 + j] = MFMA16(aq[i][0], b1[j][0], acc[i][2 + j]);
    WAIT_LGKM0();
    #pragma unroll
    for (int i = 0; i < 4; ++i)
      #pragma unroll
      for (int j = 0; j < 2; ++j)
        acc[i][2 + j] = MFMA16(aq[i][1], b1[j][1], acc[i][2 + j]);
    __builtin_amdgcn_s_setprio(0);
    BAR();
    // ---- P7 (mirror of P3)
    #pragma unroll
    for (int i = 0; i < 4; ++i) aq[i][0] = rdA(As1, 4 + i, 0);
    ORDER();
    #pragma unroll
    for (int i = 0; i < 4; ++i) aq[i][1] = rdA(As1, 4 + i, 1);
    if (pre) stage_half(Bg, n0, t + 3, Bs1);
    WAIT_LGKM(4);
    __builtin_amdgcn_s_setprio(1);
    #pragma unroll
    for (int i = 0; i < 4; ++i)
      #pragma unroll
      for (int j = 0; j < 2; ++j)
        acc[4 + i][j] = MFMA16(aq[i][0], b0[j][0], acc[4 + i][j]);
    WAIT_LGKM0();
    #pragma unroll
    for (int i = 0; i < 4; ++i)
      #pragma unroll
      for (int j = 0; j < 2; ++j)
        acc[4 + i][j] = MFMA16(aq[i][1], b0[j][1], acc[4 + i][j]);
    __builtin_amdgcn_s_setprio(0);
    BAR();
    // ---- P8
    if (pre) stage_half(Bg, n0 + 128, t + 3, Bs1 + 8192);
    __builtin_amdgcn_s_setprio(1);
    #pragma unroll
    for (int kk = 0; kk < 2; ++kk)
      #pragma unroll
      for (int i = 0; i < 4; ++i)
        #pragma unroll
        for (int j = 0; j < 2; ++j)
          acc[4 + i][2 + j] = MFMA16(aq[i][kk], b1[j][kk], acc[4 + i][2 + j]);
    __builtin_amdgcn_s_setprio(0);
    WAIT_VM(6);
    BAR();
  }

  // epilogue (16x16 C/D layout)
  if (MODE == 0 && z == 2) {
    unsigned short* vt = OutB + (size_t)2 * MROWS * DIMS;
    #pragma unroll
    for (int i = 0; i < 8; ++i) {
      const int row0 = m0 + i * 32 + wm * 16 + hi * 4;
      const int bb = row0 >> 13;
      const int s0 = row0 & (SEQ - 1);
      #pragma unroll
      for (int j = 0; j < 4; ++j) {
        const int colg = n0 + j * 64 + wn * 16 + lo;
        ushort4 pk;
        pk.x = f2bf(acc[i][j][0]); pk.y = f2bf(acc[i][j][1]);
        pk.z = f2bf(acc[i][j][2]); pk.w = f2bf(acc[i][j][3]);
        *(ushort4*)&vt[(((size_t)(bb * 2048 + colg)) << 13) + s0] = pk;
      }
    }
  } else {
    unsigned short* outb = (MODE == 0) ? (OutB + (size_t)z * MROWS * DIMS)
                                       : (unsigned short*)nullptr;
    #pragma unroll
    for (int i = 0; i < 8; ++i) {
      #pragma unroll
      for (int rr = 0; rr < 4; ++rr) {
        const int row = m0 + i * 32 + wm * 16 + hi * 4 + rr;
        const int s = row & (SEQ - 1);
        if (MODE == 1) {
          float* o = OutF + (size_t)row * DIMS + n0;
          #pragma unroll
          for (int j = 0; j < 4; ++j) o[j * 64 + wn * 16 + lo] = acc[i][j][rr];
        } else {  // z < 2: RoPE
          unsigned short* o = outb + (size_t)row * DIMS + n0;
          const int d = wn * 16 + lo;  // < 64
          const float cc = cosT[s * 64 + d], sn = sinT[s * 64 + d];
          #pragma unroll
          for (int p = 0; p < 2; ++p) {
            const float v1 = acc[i][2 * p][rr], v2 = acc[i][2 * p + 1][rr];
            o[p * 128 + d]      = f2bf(v1 * cc - v2 * sn);
            o[p * 128 + d + 64] = f2bf(v2 * cc + v1 * sn);
          }
        }
      }
    }
  }
}

// ---------------- block sliding-window attention (R10 + 2-deep K/V prefetch) --------
// grid: B*C*H = 1024 blocks; block = 512 threads = 8 waves; wave = 32 q-rows.
// K staged [64 keys][128 d], V staged [128 d][64 keys] from pre-transposed Vt;
// TRIPLE-buffered via global_load_lds (96KB + Psm 36.8KB = 133KB, still 1 block/CU):
// stage(t+2) issued at tile t -> each stage has ~2 tile-computes to land.
// vmcnt ladder: steady WAIT(8) ({t+1,t+2} in flight); tail WAIT(4)/WAIT(0).
// End-of-iter BAR protects buf (t+2)%3 (last used by tile t-1, drained at its BAR).
// Per-wave causal skip for fully-masked current-chunk tiles.
__global__ __launch_bounds__(512) void attn(
    const unsigned short* __restrict__ Qb,
    const unsigned short* __restrict__ Kb,
    const unsigned short* __restrict__ Vt,
    unsigned short* __restrict__ AO) {
  __shared__ unsigned short Ksm[3][64 * 128];
  __shared__ unsigned short Vsm[3][128 * 64];
  __shared__ unsigned short Psm[8 * 32 * 72];  // per wave [32 q][64 k + 8 pad]

  const int bid = blockIdx.x;
  const int h = bid & 15;
  const int c = (bid >> 4) & 31;
  const int b = bid >> 9;
  const int tid = threadIdx.x;
  const int wid = tid >> 6, lane = tid & 63;
  const int lo = lane & 15, hi = lane >> 4;
  const float SCALE = 0.08838834764831845f;  // 1/sqrt(128)

  // hoist Q fragments into registers
  bf16x8 qf[2][4];
  {
    const size_t base = ((size_t)(b * SEQ + c * WINW + wid * 32 + lo)) * DIMS + h * HD;
    #pragma unroll
    for (int m = 0; m < 2; ++m)
      #pragma unroll
      for (int ks = 0; ks < 4; ++ks)
        qf[m][ks] = *(const bf16x8*)&Qb[base + (size_t)m * 16 * DIMS + ks * 32 + hi * 8];
  }

  f32x4 O[2][8];
  float mrow[2][4], lrow[2][4];
  #pragma unroll
  for (int m = 0; m < 2; ++m) {
    #pragma unroll
    for (int n = 0; n < 8; ++n) O[m][n] = (f32x4){0.f, 0.f, 0.f, 0.f};
    #pragma unroll
    for (int r = 0; r < 4; ++r) { mrow[m][r] = -INFINITY; lrow[m][r] = 0.f; }
  }

  unsigned short* Pw = Psm + wid * 32 * 72;
  const int t0 = (c == 0) ? 4 : 0;  // block-uniform: chunk 0 has no previous chunk
  const int tend = 7;               // inclusive

  const unsigned short* Kg0 = Kb + ((size_t)(b * SEQ + (c - 1) * WINW)) * DIMS + h * HD;
  const unsigned short* Vg0 = Vt + (((size_t)(b * 2048 + h * HD)) << 13) + (c - 1) * WINW;

  auto stageKV = [&](int t) {
    const int pb = t % 3;
    #pragma unroll
    for (int p = 0; p < 2; ++p) {  // K: 64 rows x 16 chunks of 16B
      const int cid = p * 512 + tid;
      const int row = cid >> 4, c16 = cid & 15;
      async16(Kg0 + (size_t)(t * 64 + row) * DIMS + ((c16 ^ (row & 7)) << 3),
              &Ksm[pb][cid * 8]);
    }
    #pragma unroll
    for (int p = 0; p < 2; ++p) {  // V^T: 128 d-rows x 8 chunks of 16B
      const int cid = p * 512 + tid;
      const int rd = cid >> 3, c8 = cid & 7;
      async16(Vg0 + ((size_t)rd << 13) + t * 64 + ((c8 ^ (rd & 7)) << 3),
              &Vsm[pb][cid * 8]);
    }
  };

  // prologue: 2 tiles in flight
  stageKV(t0);
  if (t0 + 1 <= tend) stageKV(t0 + 1);
  for (int t = t0; t <= tend; ++t) {
    const int pb = t % 3;
    if (t + 2 <= tend) { stageKV(t + 2); WAIT_VM(8); }
    else if (t + 1 <= tend) { WAIT_VM(4); }
    else { WAIT_VM(0); }
    BAR();

    // per-wave causal skip: tile fully masked for this wave's 32 q-rows?
    const bool active = (t < 4) || (((t - 4) << 6) <= wid * 32 + 31);
    if (active) {
      // S = Q @ K^T  (64 keys)
      f32x4 S[2][4];
      #pragma unroll
      for (int m = 0; m < 2; ++m)
        #pragma unroll
        for (int n = 0; n < 4; ++n)
          S[m][n] = (f32x4){0.f, 0.f, 0.f, 0.f};
      const char* Kbase = (const char*)&Ksm[pb][0];
      #pragma unroll
      for (int ks = 0; ks < 4; ++ks) {
        bf16x8 kf[4];
        #pragma unroll
        for (int n = 0; n < 4; ++n)
          kf[n] = *(const bf16x8*)(Kbase + (n * 16 + lo) * 256 +
                                   (((ks * 4 + hi) ^ (lo & 7)) << 4));
        #pragma unroll
        for (int m = 0; m < 2; ++m)
          #pragma unroll
          for (int n = 0; n < 4; ++n)
            S[m][n] = MFMA16(qf[m][ks], kf[n], S[m][n]);
      }

      // mask + per-row tile max
      float tmax[2][4];
      #pragma unroll
      for (int m = 0; m < 2; ++m) {
        #pragma unroll
        for (int r = 0; r < 4; ++r) {
          const int qrow = wid * 32 + m * 16 + hi * 4 + r;
          float tm = -INFINITY;
          #pragma unroll
          for (int n = 0; n < 4; ++n) {
            const int kc = t * 64 + n * 16 + lo;
            float v = S[m][n][r] * SCALE;
            const bool ok = (kc < WINW) ? (c > 0) : ((kc - WINW) <= qrow);
            v = ok ? v : -INFINITY;
            S[m][n][r] = v;
            tm = fmaxf(tm, v);
          }
          tm = fmaxf(tm, __shfl_xor(tm, 1));
          tm = fmaxf(tm, __shfl_xor(tm, 2));
          tm = fmaxf(tm, __shfl_xor(tm, 4));
          tm = fmaxf(tm, __shfl_xor(tm, 8));
          tmax[m][r] = tm;
        }
      }
      // T13 defer-max: skip rescale when all rows drift <= 8
      float need = -INFINITY;
      #pragma unroll
      for (int m = 0; m < 2; ++m)
        #pragma unroll
        for (int r = 0; r < 4; ++r)
          need = fmaxf(need, tmax[m][r] - mrow[m][r]);
      const bool fast = __all(need <= 8.0f);

      #pragma unroll
      for (int m = 0; m < 2; ++m) {
        #pragma unroll
        for (int r = 0; r < 4; ++r) {
          float mused = mrow[m][r];
          if (!fast) {
            mused = fmaxf(mused, tmax[m][r]);
            const float corr = __expf(mrow[m][r] - mused);
            lrow[m][r] *= corr;
            #pragma unroll
            for (int n = 0; n < 8; ++n) O[m][n][r] *= corr;
            mrow[m][r] = mused;
          }
          float rsum = 0.f;
          #pragma unroll
          for (int n = 0; n < 4; ++n) {
            const float p = __expf(S[m][n][r] - mused);
            S[m][n][r] = p;
            rsum += p;
          }
          rsum += __shfl_xor(rsum, 1);
          rsum += __shfl_xor(rsum, 2);
          rsum += __shfl_xor(rsum, 4);
          rsum += __shfl_xor(rsum, 8);
          lrow[m][r] += rsum;
          #pragma unroll
          for (int n = 0; n < 4; ++n)
            Pw[(m * 16 + hi * 4 + r) * 72 + n * 16 + lo] = f2bf(S[m][n][r]);
        }
      }
      asm volatile("" ::: "memory");  // keep P stores before P reads (DS in-order per wave)

      // O += P @ V
      const char* Vbase = (const char*)&Vsm[pb][0];
      #pragma unroll
      for (int kk = 0; kk < 2; ++kk) {
        const int ko = kk * 32 + hi * 8;
        bf16x8 pf[2], vf[8];
        #pragma unroll
        for (int m = 0; m < 2; ++m)
          pf[m] = *(const bf16x8*)&Pw[(m * 16 + lo) * 72 + ko];
        #pragma unroll
        for (int n = 0; n < 8; ++n)
          vf[n] = *(const bf16x8*)(Vbase + (n * 16 + lo) * 128 +
                                   (((kk * 4 + hi) ^ (lo & 7)) << 4));
        #pragma unroll
        for (int m = 0; m < 2; ++m)
          #pragma unroll
          for (int n = 0; n < 8; ++n)
            O[m][n] = MFMA16(pf[m], vf[n], O[m][n]);
      }
    }
    BAR();
  }

  // normalize + write bf16 attention output [B,S,H*D]
  #pragma unroll
  for (int m = 0; m < 2; ++m) {
    #pragma unroll
    for (int r = 0; r < 4; ++r) {
      const float inv = 1.f / lrow[m][r];
      const size_t row = (size_t)(b * SEQ + c * WINW + wid * 32 + m * 16 + hi * 4 + r);
      unsigned short* o = AO + row * DIMS + h * HD;
      #pragma unroll
      for (int n = 0; n < 8; ++n)
        o[n * 16 + lo] = f2bf(O[m][n][r] * inv);
    }
  }
}

extern "C" void kernel_launch(void* const* d_in, const int* in_sizes, int n_in,
                              void* d_out, int out_size, void* d_ws, size_t ws_size,
                              hipStream_t stream) {
  const float* H  = (const float*)d_in[0];
  const float* Wq = (const float*)d_in[1];
  const float* Wk = (const float*)d_in[2];
  const float* Wv = (const float*)d_in[3];
  const float* Wo = (const float*)d_in[4];
  float* out = (float*)d_out;

  // workspace layout (373.3 MB total)
  unsigned short* Wt  = (unsigned short*)d_ws;                  // 4*2048*2048 bf16
  unsigned short* Hb  = Wt + (size_t)4 * DIMS * DIMS;           // 16384*2048 bf16
  unsigned short* QKV = Hb + (size_t)MROWS * DIMS;              // 3 x 16384*2048 bf16 (z=2 = Vt)
  unsigned short* AO  = QKV + (size_t)3 * MROWS * DIMS;         // 16384*2048 bf16
  float* cosT = (float*)(AO + (size_t)MROWS * DIMS);            // 8192*64 f32
  float* sinT = cosT + (size_t)SEQ * 64;

  prep<<<8192, 256, 0, stream>>>(Wq, Wk, Wv, Wo, H, Wt, Hb, cosT, sinT);
  gemm256<0><<<1536, 512, 0, stream>>>(Hb, Wt, QKV, nullptr, cosT, sinT);
  attn<<<dim3(1024), 512, 0, stream>>>(QKV, QKV + (size_t)MROWS * DIMS,
                                       QKV + (size_t)2 * MROWS * DIMS, AO);
  gemm256<1><<<512, 512, 0, stream>>>(AO, Wt, nullptr, out, cosT, sinT);
}

// Round 16
// 697.128 us; speedup vs baseline: 1.0016x; 1.0016x over previous
//
#include <hip/hip_runtime.h>
#include <cmath>

#define DIMS 2048
#define SEQ  8192
#define NB   2
#define HEADS 16
#define HD   128
#define WINW 256
#define MROWS 16384  // NB*SEQ
#define NCH  32      // SEQ/WINW

using bf16x8 = __attribute__((ext_vector_type(8))) short;
using f32x4  = __attribute__((ext_vector_type(4))) float;

__device__ __forceinline__ unsigned short f2bf(float f) {
  unsigned int u = __float_as_uint(f);
  u += 0x7FFF + ((u >> 16) & 1);
  return (unsigned short)(u >> 16);
}

__device__ __forceinline__ void async16(const unsigned short* g, unsigned short* l) {
  __builtin_amdgcn_global_load_lds((const __attribute__((address_space(1))) void*)g,
                                   (__attribute__((address_space(3))) void*)l,
                                   16, 0, 0);
}

#define BAR() __builtin_amdgcn_s_barrier()
#define WAIT_LGKM0() do { asm volatile("s_waitcnt lgkmcnt(0)" ::: "memory"); \
                          __builtin_amdgcn_sched_barrier(0); } while (0)
#define WAIT_LGKM(n) do { asm volatile("s_waitcnt lgkmcnt(" #n ")" ::: "memory"); \
                          __builtin_amdgcn_sched_barrier(0); } while (0)
#define ORDER() asm volatile("" ::: "memory")
#define WAIT_VM(n) asm volatile("s_waitcnt vmcnt(" #n ")" ::: "memory")
#define MFMA16(a, b, c) __builtin_amdgcn_mfma_f32_16x16x32_bf16(a, b, c, 0, 0, 0)

// ---------------- fused prep: weight transpose+convert / hidden f32->bf16 / RoPE table
// At HBM floor (~300MB traffic ~= 48us).
__global__ __launch_bounds__(256) void prep(
    const float* __restrict__ w0, const float* __restrict__ w1,
    const float* __restrict__ w2, const float* __restrict__ w3,
    const float* __restrict__ H,
    unsigned short* __restrict__ Wt, unsigned short* __restrict__ Hb,
    float* __restrict__ cosT, float* __restrict__ sinT) {
  __shared__ unsigned short tile[64][65];
  const int bid = blockIdx.x;
  const int t = threadIdx.x;
  if (bid < 4096) {
    const int z = bid & 3;
    const int rest = bid >> 2;
    const int n0 = (rest & 31) * 64, k0 = (rest >> 5) * 64;
    const float* W = (z == 0) ? w0 : (z == 1) ? w1 : (z == 2) ? w2 : w3;
    unsigned short* O = Wt + (size_t)z * DIMS * DIMS;
    #pragma unroll
    for (int p = 0; p < 16; ++p) {
      int i = p * 4 + (t >> 6);
      int j = t & 63;
      tile[i][j] = f2bf(W[(size_t)(k0 + i) * DIMS + n0 + j]);
    }
    __syncthreads();
    #pragma unroll
    for (int p = 0; p < 16; ++p) {
      int a = p * 4 + (t >> 6);
      int b = t & 63;
      O[(size_t)(n0 + a) * DIMS + k0 + b] = tile[b][a];
    }
  } else if (bid < 6144) {
    const long n4 = (long)MROWS * DIMS / 4;
    long i = (long)(bid - 4096) * 256 + t;
    for (; i < n4; i += 524288) {
      float4 v = ((const float4*)H)[i];
      ushort4 o;
      o.x = f2bf(v.x); o.y = f2bf(v.y); o.z = f2bf(v.z); o.w = f2bf(v.w);
      ((ushort4*)Hb)[i] = o;
    }
  } else {
    int tl = (bid - 6144) * 256 + t;  // 524288 total
    int pos = tl >> 6, i = tl & 63;
    float inv = powf(10000.0f, -(float)i / 64.0f);
    float ang = (float)pos * inv;
    float s, cc;
    __sincosf(ang, &s, &cc);
    cosT[tl] = cc;
    sinT[tl] = s;
  }
}

// ---------------- 256x256 8-phase GEMM (R11 exact: R5 schedule + split-lgkm) --------
// Measured best: QKV 383us, 0 conflicts, MfmaUtil 49%. Register budget HARD 256/wave:
// no cross-phase fragment liveness (R7/R9 spilled); no phase merging (R12 -2%); no
// 32x32 MFMA (R6 conflicts). DO NOT restructure.
template<int MODE>
__global__ __launch_bounds__(512, 2) void gemm256(
    const unsigned short* __restrict__ A,
    const unsigned short* __restrict__ WtAll,
    unsigned short* __restrict__ OutB,
    float* __restrict__ OutF,
    const float* __restrict__ cosT,
    const float* __restrict__ sinT) {
  __shared__ __align__(1024) unsigned short lds[65536];  // 128 KiB
  unsigned short* const As0 = lds;           // buf0 A [256][64]
  unsigned short* const Bs0 = lds + 16384;   // buf0 B
  unsigned short* const As1 = lds + 32768;   // buf1 A
  unsigned short* const Bs1 = lds + 49152;   // buf1 B

  const int tid = threadIdx.x;
  const int wid = tid >> 6, lane = tid & 63;
  const int lo = lane & 15, hi = lane >> 4;
  const int wm = wid >> 2, wn = wid & 3;
  const int flip = (lo & 7) << 4;  // read-side XOR: byte ^= (row&7)<<4

  // T1: bijective XCD swizzle (grid % 8 == 0 for both modes)
  const int nwg = gridDim.x;
  const int orig = blockIdx.x;
  const int bid = (orig & 7) * (nwg >> 3) + (orig >> 3);

  // z-major mapping: per XCD ~24 A-panels + one z's B matrix in L2
  int by, bx, z;
  if (MODE == 0) {
    z = bid >> 9;
    by = (bid & 511) >> 3;
    bx = bid & 7;
  } else {
    by = bid >> 3; bx = bid & 7; z = 3;
  }
  const int m0 = by * 256, n0 = bx * 256;
  const unsigned short* const Ag = A;
  const unsigned short* const Bg = WtAll + (size_t)z * DIMS * DIMS;

  f32x4 acc[8][4];
  #pragma unroll
  for (int i = 0; i < 8; ++i)
    #pragma unroll
    for (int j = 0; j < 4; ++j)
      acc[i][j] = (f32x4){0.f, 0.f, 0.f, 0.f};

  auto stage_half = [&](const unsigned short* __restrict__ G, int grow0, int tile,
                        unsigned short* dst) {
    const int k0 = tile * 64;
    #pragma unroll
    for (int h8 = 0; h8 < 2; ++h8) {
      const int c = h8 * 8 + wid;
      const int row = c * 8 + (lane >> 3);
      const int col8 = (lane & 7) ^ (lane >> 3);
      async16(G + (size_t)(grow0 + row) * DIMS + k0 + col8 * 8, dst + c * 512);
    }
  };
  auto rdA = [&](const unsigned short* base, int i, int kk) -> bf16x8 {
    const int r = i * 32 + wm * 16 + lo;
    const int cb = (kk * 64 + hi * 16) ^ flip;
    return *(const bf16x8*)((const char*)base + r * 128 + cb);
  };
  auto rdB = [&](const unsigned short* base, int j, int kk) -> bf16x8 {
    const int r = j * 64 + wn * 16 + lo;
    const int cb = (kk * 64 + hi * 16) ^ flip;
    return *(const bf16x8*)((const char*)base + r * 128 + cb);
  };

  bf16x8 aq[4][2], b0[2][2], b1[2][2];

  // prologue: tile0 full + {A0,B0,B1}(1); vmcnt(6) => tile0 landed, 3 halves in flight
  stage_half(Ag, m0,       0, As0);
  stage_half(Bg, n0,       0, Bs0);
  stage_half(Ag, m0 + 128, 0, As0 + 8192);
  stage_half(Bg, n0 + 128, 0, Bs0 + 8192);
  stage_half(Ag, m0,       1, As1);
  stage_half(Bg, n0,       1, Bs1);
  stage_half(Bg, n0 + 128, 1, Bs1 + 8192);
  WAIT_VM(6);
  BAR();

  #pragma unroll 1
  for (int it = 0; it < 16; ++it) {
    const int t = 2 * it;
    const bool pre = (it < 15);
    // ---- P1: aq+b0 (kk0 then kk1); stage A1(t+1); kk0 MFMA under kk1-read latency
    #pragma unroll
    for (int i = 0; i < 4; ++i) aq[i][0] = rdA(As0, i, 0);
    #pragma unroll
    for (int j = 0; j < 2; ++j) b0[j][0] = rdB(Bs0, j, 0);
    ORDER();
    #pragma unroll
    for (int i = 0; i < 4; ++i) aq[i][1] = rdA(As0, i, 1);
    #pragma unroll
    for (int j = 0; j < 2; ++j) b0[j][1] = rdB(Bs0, j, 1);
    stage_half(Ag, m0 + 128, t + 1, As1 + 8192);
    WAIT_LGKM(6);
    __builtin_amdgcn_s_setprio(1);
    #pragma unroll
    for (int i = 0; i < 4; ++i)
      #pragma unroll
      for (int j = 0; j < 2; ++j)
        acc[i][j] = MFMA16(aq[i][0], b0[j][0], acc[i][j]);
    WAIT_LGKM0();
    #pragma unroll
    for (int i = 0; i < 4; ++i)
      #pragma unroll
      for (int j = 0; j < 2; ++j)
        acc[i][j] = MFMA16(aq[i][1], b0[j][1], acc[i][j]);
    __builtin_amdgcn_s_setprio(0);
    BAR();
    // ---- P2: b1 (kk0, kk1); stage A0(t+2)
    #pragma unroll
    for (int j = 0; j < 2; ++j) b1[j][0] = rdB(Bs0, 2 + j, 0);
    ORDER();
    #pragma unroll
    for (int j = 0; j < 2; ++j) b1[j][1] = rdB(Bs0, 2 + j, 1);
    if (pre) stage_half(Ag, m0, t + 2, As0);
    WAIT_LGKM(2);
    __builtin_amdgcn_s_setprio(1);
    #pragma unroll
    for (int i = 0; i < 4; ++i)
      #pragma unroll
      for (int j = 0; j < 2; ++j)
        acc[i][2 + j] = MFMA16(aq[i][0], b1[j][0], acc[i][2 + j]);
    WAIT_LGKM0();
    #pragma unroll
    for (int i = 0; i < 4; ++i)
      #pragma unroll
      for (int j = 0; j < 2; ++j)
        acc[i][2 + j] = MFMA16(aq[i][1], b1[j][1], acc[i][2 + j]);
    __builtin_amdgcn_s_setprio(0);
    BAR();
    // ---- P3: aq half1 (kk0, kk1); stage B0(t+2)
    #pragma unroll
    for (int i = 0; i < 4; ++i) aq[i][0] = rdA(As0, 4 + i, 0);
    ORDER();
    #pragma unroll
    for (int i = 0; i < 4; ++i) aq[i][1] = rdA(As0, 4 + i, 1);
    if (pre) stage_half(Bg, n0, t + 2, Bs0);
    WAIT_LGKM(4);
    __builtin_amdgcn_s_setprio(1);
    #pragma unroll
    for (int i = 0; i < 4; ++i)
      #pragma unroll
      for (int j = 0; j < 2; ++j)
        acc[4 + i][j] = MFMA16(aq[i][0], b0[j][0], acc[4 + i][j]);
    WAIT_LGKM0();
    #pragma unroll
    for (int i = 0; i < 4; ++i)
      #pragma unroll
      for (int j = 0; j < 2; ++j)
        acc[4 + i][j] = MFMA16(aq[i][1], b0[j][1], acc[4 + i][j]);
    __builtin_amdgcn_s_setprio(0);
    BAR();
    // ---- P4: stage B1(t+2); MFMA; counted vmcnt
    if (pre) stage_half(Bg, n0 + 128, t + 2, Bs0 + 8192);
    __builtin_amdgcn_s_setprio(1);
    #pragma unroll
    for (int kk = 0; kk < 2; ++kk)
      #pragma unroll
      for (int i = 0; i < 4; ++i)
        #pragma unroll
        for (int j = 0; j < 2; ++j)
          acc[4 + i][2 + j] = MFMA16(aq[i][kk], b1[j][kk], acc[4 + i][2 + j]);
    __builtin_amdgcn_s_setprio(0);
    if (it == 15) { WAIT_VM(0); } else { WAIT_VM(6); }
    BAR();
    // ---- P5 (buf1 mirror of P1)
    #pragma unroll
    for (int i = 0; i < 4; ++i) aq[i][0] = rdA(As1, i, 0);
    #pragma unroll
    for (int j = 0; j < 2; ++j) b0[j][0] = rdB(Bs1, j, 0);
    ORDER();
    #pragma unroll
    for (int i = 0; i < 4; ++i) aq[i][1] = rdA(As1, i, 1);
    #pragma unroll
    for (int j = 0; j < 2; ++j) b0[j][1] = rdB(Bs1, j, 1);
    if (pre) stage_half(Ag, m0 + 128, t + 2, As0 + 8192);
    WAIT_LGKM(6);
    __builtin_amdgcn_s_setprio(1);
    #pragma unroll
    for (int i = 0; i < 4; ++i)
      #pragma unroll
      for (int j = 0; j < 2; ++j)
        acc[i][j] = MFMA16(aq[i][0], b0[j][0], acc[i][j]);
    WAIT_LGKM0();
    #pragma unroll
    for (int i = 0; i < 4; ++i)
      #pragma unroll
      for (int j = 0; j < 2; ++j)
        acc[i][j] = MFMA16(aq[i][1], b0[j][1], acc[i][j]);
    __builtin_amdgcn_s_setprio(0);
    BAR();
    // ---- P6 (mirror of P2)
    #pragma unroll
    for (int j = 0; j < 2; ++j) b1[j][0] = rdB(Bs1, 2 + j, 0);
    ORDER();
    #pragma unroll
    for (int j = 0; j < 2; ++j) b1[j][1] = rdB(Bs1, 2 + j, 1);
    if (pre) stage_half(Ag, m0, t + 3, As1);
    WAIT_LGKM(2);
    __builtin_amdgcn_s_setprio(1);
    #pragma unroll
    for (int i = 0; i < 4; ++i)
      #pragma unroll
      for (int j = 0; j < 2; ++j)
        acc[i][2 + j] = MFMA16(aq[i][0], b1[j][0], acc[i][2 + j]);
    WAIT_LGKM0();
    #pragma unroll
    for (int i = 0; i < 4; ++i)
      #pragma unroll
      for (int j = 0; j < 2; ++j)
        acc[i][2 + j] = MFMA16(aq[i][1], b1[j][1], acc[i][2 + j]);
    __builtin_amdgcn_s_setprio(0);
    BAR();
    // ---- P7 (mirror of P3)
    #pragma unroll
    for (int i = 0; i < 4; ++i) aq[i][0] = rdA(As1, 4 + i, 0);
    ORDER();
    #pragma unroll
    for (int i = 0; i < 4; ++i) aq[i][1] = rdA(As1, 4 + i, 1);
    if (pre) stage_half(Bg, n0, t + 3, Bs1);
    WAIT_LGKM(4);
    __builtin_amdgcn_s_setprio(1);
    #pragma unroll
    for (int i = 0; i < 4; ++i)
      #pragma unroll
      for (int j = 0; j < 2; ++j)
        acc[4 + i][j] = MFMA16(aq[i][0], b0[j][0], acc[4 + i][j]);
    WAIT_LGKM0();
    #pragma unroll
    for (int i = 0; i < 4; ++i)
      #pragma unroll
      for (int j = 0; j < 2; ++j)
        acc[4 + i][j] = MFMA16(aq[i][1], b0[j][1], acc[4 + i][j]);
    __builtin_amdgcn_s_setprio(0);
    BAR();
    // ---- P8
    if (pre) stage_half(Bg, n0 + 128, t + 3, Bs1 + 8192);
    __builtin_amdgcn_s_setprio(1);
    #pragma unroll
    for (int kk = 0; kk < 2; ++kk)
      #pragma unroll
      for (int i = 0; i < 4; ++i)
        #pragma unroll
        for (int j = 0; j < 2; ++j)
          acc[4 + i][2 + j] = MFMA16(aq[i][kk], b1[j][kk], acc[4 + i][2 + j]);
    __builtin_amdgcn_s_setprio(0);
    WAIT_VM(6);
    BAR();
  }

  // epilogue (16x16 C/D layout)
  if (MODE == 0 && z == 2) {
    unsigned short* vt = OutB + (size_t)2 * MROWS * DIMS;
    #pragma unroll
    for (int i = 0; i < 8; ++i) {
      const int row0 = m0 + i * 32 + wm * 16 + hi * 4;
      const int bb = row0 >> 13;
      const int s0 = row0 & (SEQ - 1);
      #pragma unroll
      for (int j = 0; j < 4; ++j) {
        const int colg = n0 + j * 64 + wn * 16 + lo;
        ushort4 pk;
        pk.x = f2bf(acc[i][j][0]); pk.y = f2bf(acc[i][j][1]);
        pk.z = f2bf(acc[i][j][2]); pk.w = f2bf(acc[i][j][3]);
        *(ushort4*)&vt[(((size_t)(bb * 2048 + colg)) << 13) + s0] = pk;
      }
    }
  } else {
    unsigned short* outb = (MODE == 0) ? (OutB + (size_t)z * MROWS * DIMS)
                                       : (unsigned short*)nullptr;
    #pragma unroll
    for (int i = 0; i < 8; ++i) {
      #pragma unroll
      for (int rr = 0; rr < 4; ++rr) {
        const int row = m0 + i * 32 + wm * 16 + hi * 4 + rr;
        const int s = row & (SEQ - 1);
        if (MODE == 1) {
          float* o = OutF + (size_t)row * DIMS + n0;
          #pragma unroll
          for (int j = 0; j < 4; ++j) o[j * 64 + wn * 16 + lo] = acc[i][j][rr];
        } else {  // z < 2: RoPE
          unsigned short* o = outb + (size_t)row * DIMS + n0;
          const int d = wn * 16 + lo;  // < 64
          const float cc = cosT[s * 64 + d], sn = sinT[s * 64 + d];
          #pragma unroll
          for (int p = 0; p < 2; ++p) {
            const float v1 = acc[i][2 * p][rr], v2 = acc[i][2 * p + 1][rr];
            o[p * 128 + d]      = f2bf(v1 * cc - v2 * sn);
            o[p * 128 + d + 64] = f2bf(v2 * cc + v1 * sn);
          }
        }
      }
    }
  }
}

// ---------------- block sliding-window attention (R10/R14 version — measured best) ---
// grid: B*C*H = 1024 blocks; block = 512 threads = 8 waves; wave = 32 q-rows.
// K staged [64 keys][128 d], V staged [128 d][64 keys] from pre-transposed Vt;
// double-buffered global_load_lds (counted vmcnt(4)), 16B-chunk XOR swizzle,
// per-wave causal skip. Triple-buffer (R15) measured neutral -> not latency-bound;
// qh-split 2-blocks/CU (R11) measured worse -> staging duplication dominates.
__global__ __launch_bounds__(512) void attn(
    const unsigned short* __restrict__ Qb,
    const unsigned short* __restrict__ Kb,
    const unsigned short* __restrict__ Vt,
    unsigned short* __restrict__ AO) {
  __shared__ unsigned short Ksm[2][64 * 128];
  __shared__ unsigned short Vsm[2][128 * 64];
  __shared__ unsigned short Psm[8 * 32 * 72];  // per wave [32 q][64 k + 8 pad]

  const int bid = blockIdx.x;
  const int h = bid & 15;
  const int c = (bid >> 4) & 31;
  const int b = bid >> 9;
  const int tid = threadIdx.x;
  const int wid = tid >> 6, lane = tid & 63;
  const int lo = lane & 15, hi = lane >> 4;
  const float SCALE = 0.08838834764831845f;  // 1/sqrt(128)

  // hoist Q fragments into registers
  bf16x8 qf[2][4];
  {
    const size_t base = ((size_t)(b * SEQ + c * WINW + wid * 32 + lo)) * DIMS + h * HD;
    #pragma unroll
    for (int m = 0; m < 2; ++m)
      #pragma unroll
      for (int ks = 0; ks < 4; ++ks)
        qf[m][ks] = *(const bf16x8*)&Qb[base + (size_t)m * 16 * DIMS + ks * 32 + hi * 8];
  }

  f32x4 O[2][8];
  float mrow[2][4], lrow[2][4];
  #pragma unroll
  for (int m = 0; m < 2; ++m) {
    #pragma unroll
    for (int n = 0; n < 8; ++n) O[m][n] = (f32x4){0.f, 0.f, 0.f, 0.f};
    #pragma unroll
    for (int r = 0; r < 4; ++r) { mrow[m][r] = -INFINITY; lrow[m][r] = 0.f; }
  }

  unsigned short* Pw = Psm + wid * 32 * 72;
  const int t0 = (c == 0) ? 4 : 0;  // block-uniform: chunk 0 has no previous chunk

  const unsigned short* Kg0 = Kb + ((size_t)(b * SEQ + (c - 1) * WINW)) * DIMS + h * HD;
  const unsigned short* Vg0 = Vt + (((size_t)(b * 2048 + h * HD)) << 13) + (c - 1) * WINW;

  auto stageKV = [&](int t, int pb) {
    #pragma unroll
    for (int p = 0; p < 2; ++p) {  // K: 64 rows x 16 chunks of 16B
      const int cid = p * 512 + tid;
      const int row = cid >> 4, c16 = cid & 15;
      async16(Kg0 + (size_t)(t * 64 + row) * DIMS + ((c16 ^ (row & 7)) << 3),
              &Ksm[pb][cid * 8]);
    }
    #pragma unroll
    for (int p = 0; p < 2; ++p) {  // V^T: 128 d-rows x 8 chunks of 16B
      const int cid = p * 512 + tid;
      const int rd = cid >> 3, c8 = cid & 7;
      async16(Vg0 + ((size_t)rd << 13) + t * 64 + ((c8 ^ (rd & 7)) << 3),
              &Vsm[pb][cid * 8]);
    }
  };

  stageKV(t0, t0 & 1);
  for (int t = t0; t < 8; ++t) {
    const int pb = t & 1;
    if (t < 7) { stageKV(t + 1, pb ^ 1); WAIT_VM(4); } else { WAIT_VM(0); }
    BAR();

    // per-wave causal skip: tile fully masked for this wave's 32 q-rows?
    const bool active = (t < 4) || (((t - 4) << 6) <= wid * 32 + 31);
    if (active) {
      // S = Q @ K^T  (64 keys)
      f32x4 S[2][4];
      #pragma unroll
      for (int m = 0; m < 2; ++m)
        #pragma unroll
        for (int n = 0; n < 4; ++n)
          S[m][n] = (f32x4){0.f, 0.f, 0.f, 0.f};
      const char* Kbase = (const char*)&Ksm[pb][0];
      #pragma unroll
      for (int ks = 0; ks < 4; ++ks) {
        bf16x8 kf[4];
        #pragma unroll
        for (int n = 0; n < 4; ++n)
          kf[n] = *(const bf16x8*)(Kbase + (n * 16 + lo) * 256 +
                                   (((ks * 4 + hi) ^ (lo & 7)) << 4));
        #pragma unroll
        for (int m = 0; m < 2; ++m)
          #pragma unroll
          for (int n = 0; n < 4; ++n)
            S[m][n] = MFMA16(qf[m][ks], kf[n], S[m][n]);
      }

      // mask + per-row tile max
      float tmax[2][4];
      #pragma unroll
      for (int m = 0; m < 2; ++m) {
        #pragma unroll
        for (int r = 0; r < 4; ++r) {
          const int qrow = wid * 32 + m * 16 + hi * 4 + r;
          float tm = -INFINITY;
          #pragma unroll
          for (int n = 0; n < 4; ++n) {
            const int kc = t * 64 + n * 16 + lo;
            float v = S[m][n][r] * SCALE;
            const bool ok = (kc < WINW) ? (c > 0) : ((kc - WINW) <= qrow);
            v = ok ? v : -INFINITY;
            S[m][n][r] = v;
            tm = fmaxf(tm, v);
          }
          tm = fmaxf(tm, __shfl_xor(tm, 1));
          tm = fmaxf(tm, __shfl_xor(tm, 2));
          tm = fmaxf(tm, __shfl_xor(tm, 4));
          tm = fmaxf(tm, __shfl_xor(tm, 8));
          tmax[m][r] = tm;
        }
      }
      // T13 defer-max: skip rescale when all rows drift <= 8
      float need = -INFINITY;
      #pragma unroll
      for (int m = 0; m < 2; ++m)
        #pragma unroll
        for (int r = 0; r < 4; ++r)
          need = fmaxf(need, tmax[m][r] - mrow[m][r]);
      const bool fast = __all(need <= 8.0f);

      #pragma unroll
      for (int m = 0; m < 2; ++m) {
        #pragma unroll
        for (int r = 0; r < 4; ++r) {
          float mused = mrow[m][r];
          if (!fast) {
            mused = fmaxf(mused, tmax[m][r]);
            const float corr = __expf(mrow[m][r] - mused);
            lrow[m][r] *= corr;
            #pragma unroll
            for (int n = 0; n < 8; ++n) O[m][n][r] *= corr;
            mrow[m][r] = mused;
          }
          float rsum = 0.f;
          #pragma unroll
          for (int n = 0; n < 4; ++n) {
            const float p = __expf(S[m][n][r] - mused);
            S[m][n][r] = p;
            rsum += p;
          }
          rsum += __shfl_xor(rsum, 1);
          rsum += __shfl_xor(rsum, 2);
          rsum += __shfl_xor(rsum, 4);
          rsum += __shfl_xor(rsum, 8);
          lrow[m][r] += rsum;
          #pragma unroll
          for (int n = 0; n < 4; ++n)
            Pw[(m * 16 + hi * 4 + r) * 72 + n * 16 + lo] = f2bf(S[m][n][r]);
        }
      }
      asm volatile("" ::: "memory");  // keep P stores before P reads (DS in-order per wave)

      // O += P @ V
      const char* Vbase = (const char*)&Vsm[pb][0];
      #pragma unroll
      for (int kk = 0; kk < 2; ++kk) {
        const int ko = kk * 32 + hi * 8;
        bf16x8 pf[2], vf[8];
        #pragma unroll
        for (int m = 0; m < 2; ++m)
          pf[m] = *(const bf16x8*)&Pw[(m * 16 + lo) * 72 + ko];
        #pragma unroll
        for (int n = 0; n < 8; ++n)
          vf[n] = *(const bf16x8*)(Vbase + (n * 16 + lo) * 128 +
                                   (((kk * 4 + hi) ^ (lo & 7)) << 4));
        #pragma unroll
        for (int m = 0; m < 2; ++m)
          #pragma unroll
          for (int n = 0; n < 8; ++n)
            O[m][n] = MFMA16(pf[m], vf[n], O[m][n]);
      }
    }
    BAR();
  }

  // normalize + write bf16 attention output [B,S,H*D]
  #pragma unroll
  for (int m = 0; m < 2; ++m) {
    #pragma unroll
    for (int r = 0; r < 4; ++r) {
      const float inv = 1.f / lrow[m][r];
      const size_t row = (size_t)(b * SEQ + c * WINW + wid * 32 + m * 16 + hi * 4 + r);
      unsigned short* o = AO + row * DIMS + h * HD;
      #pragma unroll
      for (int n = 0; n < 8; ++n)
        o[n * 16 + lo] = f2bf(O[m][n][r] * inv);
    }
  }
}

extern "C" void kernel_launch(void* const* d_in, const int* in_sizes, int n_in,
                              void* d_out, int out_size, void* d_ws, size_t ws_size,
                              hipStream_t stream) {
  const float* H  = (const float*)d_in[0];
  const float* Wq = (const float*)d_in[1];
  const float* Wk = (const float*)d_in[2];
  const float* Wv = (const float*)d_in[3];
  const float* Wo = (const float*)d_in[4];
  float* out = (float*)d_out;

  // workspace layout (373.3 MB total)
  unsigned short* Wt  = (unsigned short*)d_ws;                  // 4*2048*2048 bf16
  unsigned short* Hb  = Wt + (size_t)4 * DIMS * DIMS;           // 16384*2048 bf16
  unsigned short* QKV = Hb + (size_t)MROWS * DIMS;              // 3 x 16384*2048 bf16 (z=2 = Vt)
  unsigned short* AO  = QKV + (size_t)3 * MROWS * DIMS;         // 16384*2048 bf16
  float* cosT = (float*)(AO + (size_t)MROWS * DIMS);            // 8192*64 f32
  float* sinT = cosT + (size_t)SEQ * 64;

  prep<<<8192, 256, 0, stream>>>(Wq, Wk, Wv, Wo, H, Wt, Hb, cosT, sinT);
  gemm256<0><<<1536, 512, 0, stream>>>(Hb, Wt, QKV, nullptr, cosT, sinT);
  attn<<<dim3(1024), 512, 0, stream>>>(QKV, QKV + (size_t)MROWS * DIMS,
                                       QKV + (size_t)2 * MROWS * DIMS, AO);
  gemm256<1><<<512, 512, 0, stream>>>(AO, Wt, nullptr, out, cosT, sinT);
}